// Round 6
// baseline (134.221 us; speedup 1.0000x reference)
//
#include <hip/hip_runtime.h>
#include <hip/hip_bf16.h>
#include <math.h>

// Problem constants (from reference: 51^3 nodes, avg degree 64)
constexpr int N_NODES = 51 * 51 * 51;        // 132651
constexpr int N_EDGES = N_NODES * 64;        // 8489664
constexpr int E_HALF  = N_EDGES / 2;         // 4244832
constexpr int NP      = (N_NODES + 255) & ~255;  // padded node count

// Degree: packed u8 counters, 4 per u32 word, ONE partition covers all nodes.
// Safe: max total degree ~110 << 255 (binomial mean 64, tail bound e^-161).
constexpr int WORDS_D8 = 36864;               // 147456 u8 slots = 144 KB LDS
// Scatter: fp16 accumulators via ds_pk_add_f16, 2 passes.
constexpr int PART_S2 = 73728;                // fp16 slots (144 KB LDS)
constexpr int NP_S2   = 2;                    // 2 * 73728 >= N_NODES
// Output: s staged fp16 in LDS, 2 pass-launches.
constexpr int PART_O   = 73728;               // fp16 entries per pass (144 KB)
constexpr int SH_LEN   = PART_O * 2;          // padded s length (147456)
constexpr int OUT_BLOCKS = 256;

__device__ __forceinline__ float h2f(ushort u) {
    return (float)__builtin_bit_cast(_Float16, u);
}
__device__ __forceinline__ ushort f2h(float f) {
    return __builtin_bit_cast(unsigned short, (_Float16)f);
}

// ================= fast path =================

// Degree histogram: single pass, packed u8 counters, no filter.
__global__ __launch_bounds__(1024) void k_deg8(const int4* __restrict__ col4,
                                               unsigned* __restrict__ partial,
                                               int Bp) {
    __shared__ unsigned cnt[WORDS_D8];
    for (int j = threadIdx.x; j < WORDS_D8; j += 1024) cnt[j] = 0u;
    __syncthreads();
    const int n4 = N_EDGES / 4;
    const int stride = Bp * 1024;
#pragma unroll 2
    for (int i = blockIdx.x * 1024 + threadIdx.x; i < n4; i += stride) {
        int4 c = col4[i];
        atomicAdd(&cnt[(unsigned)c.x >> 2], 1u << (((unsigned)c.x & 3u) << 3));
        atomicAdd(&cnt[(unsigned)c.y >> 2], 1u << (((unsigned)c.y & 3u) << 3));
        atomicAdd(&cnt[(unsigned)c.z >> 2], 1u << (((unsigned)c.z & 3u) << 3));
        atomicAdd(&cnt[(unsigned)c.w >> 2], 1u << (((unsigned)c.w & 3u) << 3));
    }
    __syncthreads();
    uint4* dst = (uint4*)(partial + (size_t)blockIdx.x * WORDS_D8);
    const uint4* src = (const uint4*)cnt;
    for (int j = threadIdx.x; j < WORDS_D8 / 4; j += 1024) dst[j] = src[j];
}

// Reduce A: deg = 1 + sum of u8 partials; dinv = rsqrt(deg); u in f32 + f16.
__global__ __launch_bounds__(256) void k_reduceA(const unsigned* __restrict__ partial,
                                                 const float* __restrict__ x,
                                                 int Bp,
                                                 float* __restrict__ dinv,
                                                 float* __restrict__ uf,
                                                 ushort* __restrict__ uh) {
    int v = blockIdx.x * 256 + threadIdx.x;
    if (v >= N_NODES) return;
    const unsigned* src = partial + ((unsigned)v >> 2);
    const int sh = ((unsigned)v & 3u) << 3;
    unsigned deg = 1;  // self-loop
#pragma unroll 8
    for (int b = 0; b < Bp; ++b) deg += (src[(size_t)b * WORDS_D8] >> sh) & 0xFFu;
    float d = rsqrtf((float)deg);
    dinv[v] = d;
    float uu = d * x[v];
    uf[v] = uu;
    uh[v] = f2h(uu);
}

// Scatter: g[col] += u[row], fp16 LDS accumulators via ds_pk_add_f16, 2 passes.
__global__ __launch_bounds__(1024) void k_scat2(const int4* __restrict__ row4,
                                                const int4* __restrict__ col4,
                                                const ushort* __restrict__ uh,
                                                ushort* __restrict__ partialH,
                                                int Bp) {
    __shared__ unsigned acc[PART_S2 / 2];      // 73728 fp16 halves
    const int p = blockIdx.x / Bp;
    const int b = blockIdx.x % Bp;
    const int base = p * PART_S2;
    for (int j = threadIdx.x; j < PART_S2 / 2; j += 1024) acc[j] = 0u;
    __syncthreads();
    const unsigned accBase = (unsigned)(uintptr_t)(&acc[0]);  // LDS byte offset
    const int n4 = N_EDGES / 4;
    const int stride = Bp * 1024;
    int i = b * 1024 + threadIdx.x;
    bool valid = i < n4;
    int4 c, r;
    if (valid) { c = col4[i]; r = row4[i]; }
    while (valid) {
        const int inext = i + stride;
        const bool vnext = inext < n4;
        int4 cn, rn;
        if (vnext) { cn = col4[inext]; rn = row4[inext]; }  // prefetch
        unsigned j;
#define SCAT1(CC, RR)                                                          \
        j = (unsigned)(CC - base);                                             \
        if (j < (unsigned)PART_S2) {                                           \
            unsigned pk = (unsigned)uh[RR] << ((j & 1u) << 4);                 \
            unsigned off = accBase + ((j >> 1) << 2);                          \
            asm volatile("ds_pk_add_f16 %0, %1" :: "v"(off), "v"(pk) : "memory"); \
        }
        SCAT1(c.x, r.x) SCAT1(c.y, r.y) SCAT1(c.z, r.z) SCAT1(c.w, r.w)
#undef SCAT1
        c = cn; r = rn; i = inext; valid = vnext;
    }
    __syncthreads();
    uint4* dst = (uint4*)(partialH + (size_t)blockIdx.x * PART_S2);
    const uint4* src = (const uint4*)acc;
    for (int j = threadIdx.x; j < PART_S2 / 8; j += 1024) dst[j] = src[j];
}

// Reduce B: t = dinv*(g+u);  s = relu(t*W0+b0)+relu(t*W1+b1), stored fp16.
__global__ __launch_bounds__(256) void k_reduceB(const ushort* __restrict__ partialH,
                                                 const float* __restrict__ dinv,
                                                 const float* __restrict__ uf,
                                                 const float* __restrict__ W,
                                                 const float* __restrict__ bb,
                                                 int Bp,
                                                 ushort* __restrict__ sh) {
    int v = blockIdx.x * 256 + threadIdx.x;
    if (v >= N_NODES) return;
    const int p = (v >= PART_S2) ? 1 : 0;
    const int j = v - p * PART_S2;
    const ushort* src = partialH + (size_t)(p * Bp) * PART_S2 + j;
    float g = 0.f;
#pragma unroll 8
    for (int b = 0; b < Bp; ++b) g += h2f(src[(size_t)b * PART_S2]);
    float t = dinv[v] * (g + uf[v]);
    float h0 = fmaxf(fmaf(t, W[0], bb[0]), 0.f);
    float h1 = fmaxf(fmaf(t, W[1], bb[1]), 0.f);
    sh[v] = f2h(h0 + h1);
}

// ================= fallback path (global atomics) =================

__global__ __launch_bounds__(256) void k_init_deg(int* __restrict__ deg) {
    int i = blockIdx.x * 256 + threadIdx.x;
    if (i < N_NODES) deg[i] = 1;
}

__global__ __launch_bounds__(256) void k_deg(const int4* __restrict__ col4,
                                             int* __restrict__ deg) {
    int i = blockIdx.x * 256 + threadIdx.x;
    const int stride = gridDim.x * 256;
    const int n4 = N_EDGES / 4;
    for (; i < n4; i += stride) {
        int4 c = col4[i];
        atomicAdd(&deg[c.x], 1); atomicAdd(&deg[c.y], 1);
        atomicAdd(&deg[c.z], 1); atomicAdd(&deg[c.w], 1);
    }
}

__global__ __launch_bounds__(256) void k_dinv(const int* __restrict__ deg,
                                              const float* __restrict__ x,
                                              float* __restrict__ dinv,
                                              float* __restrict__ t) {
    int i = blockIdx.x * 256 + threadIdx.x;
    if (i >= N_NODES) return;
    float d = rsqrtf((float)deg[i]);
    dinv[i] = d;
    t[i] = d * d * x[i];
}

__global__ __launch_bounds__(256) void k_scatter(const int4* __restrict__ row4,
                                                 const int4* __restrict__ col4,
                                                 const float* __restrict__ x,
                                                 const float* __restrict__ dinv,
                                                 float* __restrict__ t) {
    int i = blockIdx.x * 256 + threadIdx.x;
    const int stride = gridDim.x * 256;
    const int n4 = N_EDGES / 4;
    for (; i < n4; i += stride) {
        int4 r = row4[i];
        int4 c = col4[i];
        atomicAdd(&t[c.x], dinv[r.x] * dinv[c.x] * x[r.x]);
        atomicAdd(&t[c.y], dinv[r.y] * dinv[c.y] * x[r.y]);
        atomicAdd(&t[c.z], dinv[r.z] * dinv[c.z] * x[r.z]);
        atomicAdd(&t[c.w], dinv[r.w] * dinv[c.w] * x[r.w]);
    }
}

__global__ __launch_bounds__(256) void k_node(const float* __restrict__ t,
                                              const float* __restrict__ W,
                                              const float* __restrict__ b,
                                              ushort* __restrict__ sh) {
    int i = blockIdx.x * 256 + threadIdx.x;
    if (i >= N_NODES) return;
    float tv = t[i];
    float h0 = fmaxf(fmaf(tv, W[0], b[0]), 0.f);
    float h1 = fmaxf(fmaf(tv, W[1], b[1]), 0.f);
    sh[i] = f2h(h0 + h1);
}

// ================= output kernel: 2 pass-launches ======

__global__ __launch_bounds__(1024) void k_out_pass(const int4* __restrict__ rowA4,
                                                   const int4* __restrict__ colA4,
                                                   const int4* __restrict__ rowB4,
                                                   const int4* __restrict__ colB4,
                                                   const ushort* __restrict__ sh,
                                                   float4* __restrict__ out,
                                                   int base, int final_pass) {
    __shared__ ushort sl[PART_O];
    {
        const uint4* src = (const uint4*)(sh + base);
        uint4* dst = (uint4*)sl;
        for (int j = threadIdx.x; j < PART_O / 8; j += 1024) dst[j] = src[j];
    }
    __syncthreads();
    const int n4 = E_HALF / 4;
    const int stride = gridDim.x * 1024;
#pragma unroll 2
    for (int i = blockIdx.x * 1024 + threadIdx.x; i < n4; i += stride) {
        int4 ra = rowA4[i], ca = colA4[i], rb = rowB4[i], cb = colB4[i];
        float c0 = 0.f, c1 = 0.f, c2 = 0.f, c3 = 0.f;
        unsigned j;
        j = (unsigned)(ra.x - base); if (j < (unsigned)PART_O) c0 += h2f(sl[j]);
        j = (unsigned)(ca.x - base); if (j < (unsigned)PART_O) c0 += h2f(sl[j]);
        j = (unsigned)(rb.x - base); if (j < (unsigned)PART_O) c0 += h2f(sl[j]);
        j = (unsigned)(cb.x - base); if (j < (unsigned)PART_O) c0 += h2f(sl[j]);
        j = (unsigned)(ra.y - base); if (j < (unsigned)PART_O) c1 += h2f(sl[j]);
        j = (unsigned)(ca.y - base); if (j < (unsigned)PART_O) c1 += h2f(sl[j]);
        j = (unsigned)(rb.y - base); if (j < (unsigned)PART_O) c1 += h2f(sl[j]);
        j = (unsigned)(cb.y - base); if (j < (unsigned)PART_O) c1 += h2f(sl[j]);
        j = (unsigned)(ra.z - base); if (j < (unsigned)PART_O) c2 += h2f(sl[j]);
        j = (unsigned)(ca.z - base); if (j < (unsigned)PART_O) c2 += h2f(sl[j]);
        j = (unsigned)(rb.z - base); if (j < (unsigned)PART_O) c2 += h2f(sl[j]);
        j = (unsigned)(cb.z - base); if (j < (unsigned)PART_O) c2 += h2f(sl[j]);
        j = (unsigned)(ra.w - base); if (j < (unsigned)PART_O) c3 += h2f(sl[j]);
        j = (unsigned)(ca.w - base); if (j < (unsigned)PART_O) c3 += h2f(sl[j]);
        j = (unsigned)(rb.w - base); if (j < (unsigned)PART_O) c3 += h2f(sl[j]);
        j = (unsigned)(cb.w - base); if (j < (unsigned)PART_O) c3 += h2f(sl[j]);
        float4 o;
        if (final_pass) {
            float4 prev = out[i];
            o.x = 1.f / (1.f + __expf(-0.5f * (prev.x + c0)));
            o.y = 1.f / (1.f + __expf(-0.5f * (prev.y + c1)));
            o.z = 1.f / (1.f + __expf(-0.5f * (prev.z + c2)));
            o.w = 1.f / (1.f + __expf(-0.5f * (prev.w + c3)));
        } else {
            o.x = c0; o.y = c1; o.z = c2; o.w = c3;
        }
        out[i] = o;
    }
}

// ================= launch =================

extern "C" void kernel_launch(void* const* d_in, const int* in_sizes, int n_in,
                              void* d_out, int out_size, void* d_ws, size_t ws_size,
                              hipStream_t stream) {
    const float* x = (const float*)d_in[0];
    const float* W = (const float*)d_in[1];
    const float* b = (const float*)d_in[2];
    const int*   ei = (const int*)d_in[3];
    const int* row = ei;
    const int* col = ei + N_EDGES;
    float* out = (float*)d_out;

    char* ws = (char*)d_ws;
    float*  dinv = (float*)(ws);                            // NP f32
    float*  uf   = (float*)(ws + (size_t)NP * 4);           // NP f32
    ushort* uh   = (ushort*)(ws + (size_t)NP * 8);          // NP f16
    ushort* sh   = (ushort*)(ws + (size_t)NP * 10);         // SH_LEN f16
    char* partialBase = ws + (size_t)NP * 10 + (size_t)SH_LEN * 2;
    size_t head = (size_t)NP * 10 + (size_t)SH_LEN * 2;
    size_t avail = (ws_size > head) ? ws_size - head : 0;

    // per-block partial = 147456 B for both deg (u8 words) and scat (f16)
    int Bp_d = (int)(avail / 147456);
    if (Bp_d > 128) Bp_d = 128;
    int Bp_s = (int)(avail / (2 * 147456));
    if (Bp_s > 128) Bp_s = 128;

    const int nodeBlocks = (N_NODES + 255) / 256;
    const int edgeBlocks = 2048;

    if (Bp_s >= 2 && Bp_d >= 2) {
        unsigned* partU = (unsigned*)partialBase;
        ushort*   partH = (ushort*)partialBase;  // reused after reduceA consumes partU
        k_deg8<<<Bp_d, 1024, 0, stream>>>((const int4*)col, partU, Bp_d);
        k_reduceA<<<nodeBlocks, 256, 0, stream>>>(partU, x, Bp_d, dinv, uf, uh);
        k_scat2<<<NP_S2 * Bp_s, 1024, 0, stream>>>((const int4*)row, (const int4*)col,
                                                   uh, partH, Bp_s);
        k_reduceB<<<nodeBlocks, 256, 0, stream>>>(partH, dinv, uf, W, b, Bp_s, sh);
    } else {
        int* deg = (int*)partialBase;  // fallback scratch
        k_init_deg<<<nodeBlocks, 256, 0, stream>>>(deg);
        k_deg<<<edgeBlocks, 256, 0, stream>>>((const int4*)col, deg);
        k_dinv<<<nodeBlocks, 256, 0, stream>>>(deg, x, dinv, uf);
        k_scatter<<<edgeBlocks, 256, 0, stream>>>((const int4*)row, (const int4*)col,
                                                  x, dinv, uf);
        k_node<<<nodeBlocks, 256, 0, stream>>>(uf, W, b, sh);
    }

    // Output: 2 pass-launches over the edge list, s staged fp16 in LDS.
    k_out_pass<<<OUT_BLOCKS, 1024, 0, stream>>>(
        (const int4*)row, (const int4*)col,
        (const int4*)(row + E_HALF), (const int4*)(col + E_HALF),
        sh, (float4*)out, 0, 0);
    k_out_pass<<<OUT_BLOCKS, 1024, 0, stream>>>(
        (const int4*)row, (const int4*)col,
        (const int4*)(row + E_HALF), (const int4*)(col + E_HALF),
        sh, (float4*)out, PART_O, 1);
}